// Round 10
// baseline (1589.161 us; speedup 1.0000x reference)
//
#include <hip/hip_runtime.h>

// LSTM: B=512, T=128, D=512, H=512, gates [i|j|f|o], FORGET_BIAS=1.0
// Persistent kernel, 256 blocks x 512 threads (8 waves), 1 block/CU.
// Waves = (gate, row-half): 16 A-reads + 32 MFMA per wave per step; B (32 cols
// x K=512) = 128 VGPR, time-shared between Wx (gemm phase) and Wh (rec phase)
// per 8-step chunk. zx kept in a 64KB LDS ring. Protocol: proven round-5/8/9
// sc1 relaxed agent atomics for h+flags, 64B-spaced flags, fence-free monotone.
// Staging uses c*256+sl16*16 chunks -> 2-way LDS bank aliasing only.

#define Tt  128
#define Dd  512
#define Hh  512
#define TC  8           // steps per chunk
#define NCH (Tt / TC)   // 16 chunks

typedef _Float16 half8 __attribute__((ext_vector_type(8)));
typedef _Float16 half4 __attribute__((ext_vector_type(4)));
typedef float    f32x4 __attribute__((ext_vector_type(4)));
typedef float    f32x2 __attribute__((ext_vector_type(2)));
typedef unsigned long long u64;

#define MF(a,b,c) __builtin_amdgcn_mfma_f32_16x16x32_f16(a,b,c,0,0,0)

// LDS map (144 KB -> 1 block/CU)
#define Z_OFF   0         // 16 KB: gate exchange [4][32] rows x 128 B (swizzled)
#define H_OFF   16384     // 32 KB: h tile, 32 rows x 1024 B (swizzled)
#define R_OFF   49152     // 64 KB: zx ring, 8 slots x 8 KB
#define X_OFF   114688    // 32 KB: x tile (swizzled)
#define SMEM_SZ 147456

__device__ __forceinline__ float sigm(float v) { return 1.0f / (1.0f + __expf(-v)); }
__device__ __forceinline__ float tanhfast(float v) {
    float e = __expf(-2.0f * fabsf(v));
    float r = (1.0f - e) / (1.0f + e);
    return (v < 0.0f) ? -r : r;
}
__device__ __forceinline__ half8 mk16(u64 a, u64 b) {
    half4 x = __builtin_bit_cast(half4, a), y = __builtin_bit_cast(half4, b);
    half8 r;
    r[0] = x[0]; r[1] = x[1]; r[2] = x[2]; r[3] = x[3];
    r[4] = y[0]; r[5] = y[1]; r[6] = y[2]; r[7] = y[3];
    return r;
}

// Pack W [1024,2048] f32 -> fragment-major f16 slices (verified rounds 2-9).
// Slice f = ct*4+gate: [hn(2)][kc(16)][lane(64)][8]; element j =
// W[koff + kc*32 + (lane>>4)*8 + j][gate*512 + ct*32 + hn*16 + (lane&15)].
__global__ __launch_bounds__(256) void pack_kernel(const float* __restrict__ W,
                                                   _Float16* __restrict__ Wxp,
                                                   _Float16* __restrict__ Whp) {
    __shared__ _Float16 Tl[512 * 32];
    const int bid = blockIdx.x, tid = threadIdx.x;
    const int which = bid >> 6;
    const int f = bid & 63, ct = f >> 2, wv = f & 3;
    const int koff = which * 512;
    const int ncol0 = wv * Hh + ct * 32;

#pragma unroll
    for (int p = 0; p < 16; ++p) {
        int row = p * 32 + (tid >> 3);
        int c4  = (tid & 7) * 4;
        float4 v = *reinterpret_cast<const float4*>(W + (size_t)(koff + row) * 2048 + ncol0 + c4);
        Tl[row * 32 + c4 + 0] = (_Float16)v.x;
        Tl[row * 32 + c4 + 1] = (_Float16)v.y;
        Tl[row * 32 + c4 + 2] = (_Float16)v.z;
        Tl[row * 32 + c4 + 3] = (_Float16)v.w;
    }
    __syncthreads();

    _Float16* dst = (which ? Whp : Wxp) + (size_t)f * 16384;
#pragma unroll
    for (int i = 0; i < 8; ++i) {
        int gi  = tid * 8 + i;
        int hn  = gi >> 10;
        int kc  = (gi >> 6) & 15;
        int ln  = gi & 63;
        int l15 = ln & 15, l16 = ln >> 4;
        half8 v;
#pragma unroll
        for (int j = 0; j < 8; ++j)
            v[j] = Tl[(kc * 32 + l16 * 8 + j) * 32 + hn * 16 + l15];
        *reinterpret_cast<half8*>(dst + (size_t)gi * 8) = v;
    }
}

// x f32 -> f16 (one pass)
__global__ __launch_bounds__(256) void xhalf_kernel(const float* __restrict__ xf,
                                                    _Float16* __restrict__ xh) {
    const size_t N = (size_t)512 * Tt * Dd;
    size_t stride = (size_t)gridDim.x * 256 * 8;
    for (size_t base = ((size_t)blockIdx.x * 256 + threadIdx.x) * 8; base < N; base += stride) {
        float4 a = *reinterpret_cast<const float4*>(xf + base);
        float4 b = *reinterpret_cast<const float4*>(xf + base + 4);
        half8 v;
        v[0] = (_Float16)a.x; v[1] = (_Float16)a.y; v[2] = (_Float16)a.z; v[3] = (_Float16)a.w;
        v[4] = (_Float16)b.x; v[5] = (_Float16)b.y; v[6] = (_Float16)b.z; v[7] = (_Float16)b.w;
        *reinterpret_cast<half8*>(xh + base) = v;
    }
}

__global__ __launch_bounds__(512, 2) void lstm_all(
    const float* __restrict__ xf, const _Float16* __restrict__ xh, int usexh,
    const _Float16* __restrict__ Wxp, const _Float16* __restrict__ Whp,
    const float* __restrict__ bias, _Float16* __restrict__ h0,
    _Float16* __restrict__ h1, unsigned int* __restrict__ flags,
    float* __restrict__ out) {

    __shared__ __align__(16) char smem[SMEM_SZ];

    const int tid = threadIdx.x, lane = tid & 63;
    const int wv8 = tid >> 6;            // wave 0..7
    const int g8  = wv8 & 3;             // gate 0..3
    const int rh  = wv8 >> 2;            // row half 0..1
    const int l15 = lane & 15, l16 = lane >> 4;
    const int bid = blockIdx.x;
    const int grp = bid & 15;                         // row group id
    const int rt = (bid & 7) * 2 + ((bid >> 3) & 1);  // row tile 0..15
    const int ct = bid >> 4;                          // col tile 0..15

    // B fragments (time-shared Wx / Wh): 32 half8 = 128 VGPR
    half8 Bf[32];   // [kc*2 + colfrag]
    const half8* wx_base = reinterpret_cast<const half8*>(Wxp) + (size_t)(ct * 4 + g8) * 2048;
    const half8* wh_base = reinterpret_cast<const half8*>(Whp) + (size_t)(ct * 4 + g8) * 2048;
    auto load_B = [&](const half8* base) {
#pragma unroll
        for (int kc = 0; kc < 16; ++kc) {
#pragma unroll
            for (int hn = 0; hn < 2; ++hn)
                Bf[kc * 2 + hn] = base[(hn * 16 + kc) * 64 + lane];
        }
    };

    const float bias0 = bias[g8 * Hh + ct * 32 + l15]      + (g8 == 2 ? 1.0f : 0.0f);
    const float bias1 = bias[g8 * Hh + ct * 32 + 16 + l15] + (g8 == 2 ? 1.0f : 0.0f);

    const int srow = tid >> 4, sl16 = tid & 15;       // staging: row 0..31, chunk 0..15
    const int erow = tid >> 4, ecol2 = (tid & 15) * 2; // pointwise: 2 cols/thread
    const int arow = rh * 16 + l15;                   // A-fragment row for this wave
    const int aswz = (arow & 7) << 4;
    float creg[2] = {0.f, 0.f};

    // stage x_t (conflict-free chunks c*256 + sl16*16)
    auto stage_x = [&](int t) {
        char* xb = smem + X_OFF + srow * 1024;
        if (usexh) {
            const _Float16* xr = xh + ((size_t)(rt * 32 + srow) * Tt + t) * Dd;
#pragma unroll
            for (int c = 0; c < 4; ++c) {
                int e = c * 128 + sl16 * 8;
                half8 v = *reinterpret_cast<const half8*>(xr + e);
                *reinterpret_cast<half8*>(xb + ((e * 2) ^ ((srow & 7) << 4))) = v;
            }
        } else {
            const float* xr = xf + ((size_t)(rt * 32 + srow) * Tt + t) * Dd;
#pragma unroll
            for (int c = 0; c < 4; ++c) {
                int e = c * 128 + sl16 * 8;
                float4 p0 = *reinterpret_cast<const float4*>(xr + e);
                float4 p1 = *reinterpret_cast<const float4*>(xr + e + 4);
                half8 v;
                v[0] = (_Float16)p0.x; v[1] = (_Float16)p0.y;
                v[2] = (_Float16)p0.z; v[3] = (_Float16)p0.w;
                v[4] = (_Float16)p1.x; v[5] = (_Float16)p1.y;
                v[6] = (_Float16)p1.z; v[7] = (_Float16)p1.w;
                *reinterpret_cast<half8*>(xb + ((e * 2) ^ ((srow & 7) << 4))) = v;
            }
        }
    };

    const int nChunks = NCH;

#pragma unroll 1
    for (int cc = 0; cc < nChunks; ++cc) {
        // ================= GEMM phase: zx = bias + x@Wx, B regs = Wx =================
        load_B(wx_base);
#pragma unroll 1
        for (int p = 0; p < TC; ++p) {
            const int t = cc * TC + p;
            stage_x(t);
            __syncthreads();

            f32x4 acc0 = {bias0, bias0, bias0, bias0};
            f32x4 acc1 = {bias1, bias1, bias1, bias1};
#pragma unroll
            for (int kc = 0; kc < 16; ++kc) {
                half8 a = *reinterpret_cast<const half8*>(
                    smem + X_OFF + arow * 1024 + ((kc * 64 + l16 * 16) ^ aswz));
                acc0 = MF(a, Bf[kc * 2 + 0], acc0);
                acc1 = MF(a, Bf[kc * 2 + 1], acc1);
            }
            // ring write (thread-private slot)
            half8 z;
#pragma unroll
            for (int r = 0; r < 4; ++r) { z[r] = (_Float16)acc0[r]; z[4 + r] = (_Float16)acc1[r]; }
            *reinterpret_cast<half8*>(smem + R_OFF + p * 8192 + wv8 * 1024 + lane * 16) = z;
            __syncthreads();      // X free for next p
        }

        // ================= recurrence phase: B regs = Wh =================
        load_B(wh_base);
#pragma unroll 1
        for (int p = 0; p < TC; ++p) {
            const int t = cc * TC + p;
            const _Float16* hin = (t & 1) ? h1 : h0;
            _Float16* hout      = (t & 1) ? h0 : h1;

            // poll producers of this row group (64B-spaced flags, sc1 relaxed)
            if (tid < 16) {
                while (__hip_atomic_load(&flags[((unsigned)grp + 16u * (unsigned)tid) * 16u],
                                         __ATOMIC_RELAXED, __HIP_MEMORY_SCOPE_AGENT)
                       < (unsigned)t)
                    __builtin_amdgcn_s_sleep(1);
            }
            __syncthreads();

            // cooperative h gather (sc1 burst), conflict-free chunk mapping
            const u64* hq = reinterpret_cast<const u64*>(hin) + (size_t)(rt * 32 + srow) * 128;
            u64 hr[8];
#pragma unroll
            for (int c = 0; c < 4; ++c) {
                hr[2 * c]     = __hip_atomic_load(hq + c * 32 + sl16 * 2,
                                    __ATOMIC_RELAXED, __HIP_MEMORY_SCOPE_AGENT);
                hr[2 * c + 1] = __hip_atomic_load(hq + c * 32 + sl16 * 2 + 1,
                                    __ATOMIC_RELAXED, __HIP_MEMORY_SCOPE_AGENT);
            }

            // acc init from zx ring (overlaps gather latency)
            f32x4 acc0, acc1;
            {
                half8 z = *reinterpret_cast<const half8*>(
                    smem + R_OFF + p * 8192 + wv8 * 1024 + lane * 16);
#pragma unroll
                for (int r = 0; r < 4; ++r) { acc0[r] = (float)z[r]; acc1[r] = (float)z[4 + r]; }
            }

            // stage h tile (waits gather)
            {
                char* hb = smem + H_OFF + srow * 1024;
#pragma unroll
                for (int c = 0; c < 4; ++c) {
                    int e = c * 128 + sl16 * 8;
                    *reinterpret_cast<half8*>(hb + ((e * 2) ^ ((srow & 7) << 4))) =
                        mk16(hr[2 * c], hr[2 * c + 1]);
                }
            }
            __syncthreads();

            // recurrence MFMAs: 16 A-reads, 32 MFMA per wave
#pragma unroll
            for (int kc = 0; kc < 16; ++kc) {
                half8 a = *reinterpret_cast<const half8*>(
                    smem + H_OFF + arow * 1024 + ((kc * 64 + l16 * 16) ^ aswz));
                acc0 = MF(a, Bf[kc * 2 + 0], acc0);
                acc1 = MF(a, Bf[kc * 2 + 1], acc1);
            }

            // Z scatter (swizzled [4][32][128B]); wave covers rows rh*16..+15
#pragma unroll
            for (int reg = 0; reg < 4; ++reg) {
                int grow = rh * 16 + l16 * 4 + reg;  // C/D: col=lane&15, row=(lane>>4)*4+reg
                int sw = (grow & 7) << 4;
                *reinterpret_cast<float*>(smem + Z_OFF + (g8 * 32 + grow) * 128
                    + ((l15 * 4) ^ sw))        = acc0[reg];
                *reinterpret_cast<float*>(smem + Z_OFF + (g8 * 32 + grow) * 128
                    + (((16 + l15) * 4) ^ sw)) = acc1[reg];
            }
            __syncthreads();

            // pointwise c/h update: 2 cols per thread
            float hv[2];
            {
                int swz = (ecol2 * 4) ^ ((erow & 7) << 4);
                f32x2 vi = *reinterpret_cast<const f32x2*>(smem + Z_OFF + (0 * 32 + erow) * 128 + swz);
                f32x2 vj = *reinterpret_cast<const f32x2*>(smem + Z_OFF + (1 * 32 + erow) * 128 + swz);
                f32x2 vf = *reinterpret_cast<const f32x2*>(smem + Z_OFF + (2 * 32 + erow) * 128 + swz);
                f32x2 vo = *reinterpret_cast<const f32x2*>(smem + Z_OFF + (3 * 32 + erow) * 128 + swz);
#pragma unroll
                for (int q = 0; q < 2; ++q) {
                    float cn = creg[q] * sigm(vf[q]) + sigm(vi[q]) * tanhfast(vj[q]);
                    creg[q] = cn;
                    hv[q] = tanhfast(cn) * sigm(vo[q]);
                }
            }
            {
                size_t off = (size_t)(rt * 32 + erow) * Hh + ct * 32 + ecol2;
                unsigned hraw = (unsigned)__builtin_bit_cast(unsigned short, (_Float16)hv[0])
                              | ((unsigned)__builtin_bit_cast(unsigned short, (_Float16)hv[1]) << 16);
                __hip_atomic_store(reinterpret_cast<unsigned*>(hout) + (off >> 1), hraw,
                                   __ATOMIC_RELAXED, __HIP_MEMORY_SCOPE_AGENT);
                if (t == Tt - 1) {
                    f32x2 fo; fo[0] = hv[0]; fo[1] = hv[1];
                    *reinterpret_cast<f32x2*>(out + off) = fo;
                }
            }

            // drain h stores (syncthreads waits vmcnt(0)), then post flag
            __syncthreads();
            if (t < Tt - 1 && tid == 0)
                __hip_atomic_store(&flags[bid * 16], (unsigned)(t + 1),
                                   __ATOMIC_RELAXED, __HIP_MEMORY_SCOPE_AGENT);
        }
    }
}

extern "C" void kernel_launch(void* const* d_in, const int* in_sizes, int n_in,
                              void* d_out, int out_size, void* d_ws, size_t ws_size,
                              hipStream_t stream) {
    const float* x  = (const float*)d_in[0];   // [512,128,512] f32
    const float* W  = (const float*)d_in[1];   // [1024,2048] f32
    const float* bb = (const float*)d_in[2];   // [2048] f32
    float* out = (float*)d_out;                // [512,512] f32

    char* ws = (char*)d_ws;
    _Float16* Wxp = (_Float16*)ws;                                   // 2 MB
    _Float16* Whp = (_Float16*)(ws + (2u << 20));                    // 2 MB
    _Float16* h0  = (_Float16*)(ws + (4u << 20));                    // 512 KB
    _Float16* h1  = (_Float16*)(ws + (4u << 20) + (512u << 10));     // 512 KB
    unsigned int* flags = (unsigned int*)(ws + (5u << 20));          // 256 x 64B
    _Float16* xh = (_Float16*)(ws + (6u << 20));                     // 64 MB (optional)

    const size_t xh_bytes = (size_t)512 * Tt * Dd * sizeof(_Float16);
    int usexh = (ws_size >= (size_t)(6u << 20) + xh_bytes) ? 1 : 0;

    hipMemsetAsync(h0, 0, (size_t)512 * Hh * sizeof(_Float16), stream);
    hipMemsetAsync((void*)flags, 0, 16384, stream);
    pack_kernel<<<128, 256, 0, stream>>>(W, Wxp, Whp);
    if (usexh) xhalf_kernel<<<4096, 256, 0, stream>>>(x, xh);
    lstm_all<<<256, 512, 0, stream>>>(x, xh, usexh, Wxp, Whp, bb, h0, h1, flags, out);
}

// Round 11
// 514.114 us; speedup vs baseline: 3.0911x; 3.0911x over previous
//
#include <hip/hip_runtime.h>

// LSTM: B=512, T=128, D=512, H=512, gates [i|j|f|o], FORGET_BIAS=1.0
// Persistent kernel, 256 blocks x 512 threads (8 waves), 1 block/CU.
// Round 9 structure (waves = gate x col-half, W fragment arrays per wave,
// zx computed 4 steps ahead into a 4-slot LDS ring, T14 split x prefetch,
// proven sc1 relaxed-atomic h/flag protocol) + conflict-free staging mapping
// (c*256 + sl16*16 chunks: 16 lanes x 16B contiguous, 0-way bank conflict).

#define Tt  128
#define Dd  512
#define Hh  512

typedef _Float16 half8 __attribute__((ext_vector_type(8)));
typedef _Float16 half4 __attribute__((ext_vector_type(4)));
typedef float    f32x4 __attribute__((ext_vector_type(4)));
typedef float    f32x2 __attribute__((ext_vector_type(2)));
typedef unsigned long long u64;

#define MF(a,b,c) __builtin_amdgcn_mfma_f32_16x16x32_f16(a,b,c,0,0,0)

// LDS map (144 KB -> 1 block/CU)
#define Z_OFF   0         // 16 KB: gate exchange [4][32] rows x 128 B (swizzled)
#define H_OFF   16384     // 32 KB: h tile, 32 rows x 1024 B (swizzled)
#define R_OFF   49152     // 32 KB: zx ring, 4 slots x 8 KB
#define X_OFF   81920     // 2 x 32 KB: x tile double buffer (swizzled)
#define SMEM_SZ 147456

__device__ __forceinline__ float sigm(float v) { return 1.0f / (1.0f + __expf(-v)); }
__device__ __forceinline__ float tanhfast(float v) {
    float e = __expf(-2.0f * fabsf(v));
    float r = (1.0f - e) / (1.0f + e);
    return (v < 0.0f) ? -r : r;
}
__device__ __forceinline__ half8 mk16(u64 a, u64 b) {
    half4 x = __builtin_bit_cast(half4, a), y = __builtin_bit_cast(half4, b);
    half8 r;
    r[0] = x[0]; r[1] = x[1]; r[2] = x[2]; r[3] = x[3];
    r[4] = y[0]; r[5] = y[1]; r[6] = y[2]; r[7] = y[3];
    return r;
}

// Pack W [1024,2048] f32 -> fragment-major f16 slices (verified rounds 2-9).
// Slice f = ct*4+gate: [hn(2)][kc(16)][lane(64)][8]; element j =
// W[koff + kc*32 + (lane>>4)*8 + j][gate*512 + ct*32 + hn*16 + (lane&15)].
__global__ __launch_bounds__(256) void pack_kernel(const float* __restrict__ W,
                                                   _Float16* __restrict__ Wxp,
                                                   _Float16* __restrict__ Whp) {
    __shared__ _Float16 Tl[512 * 32];
    const int bid = blockIdx.x, tid = threadIdx.x;
    const int which = bid >> 6;
    const int f = bid & 63, ct = f >> 2, wv = f & 3;
    const int koff = which * 512;
    const int ncol0 = wv * Hh + ct * 32;

#pragma unroll
    for (int p = 0; p < 16; ++p) {
        int row = p * 32 + (tid >> 3);
        int c4  = (tid & 7) * 4;
        float4 v = *reinterpret_cast<const float4*>(W + (size_t)(koff + row) * 2048 + ncol0 + c4);
        Tl[row * 32 + c4 + 0] = (_Float16)v.x;
        Tl[row * 32 + c4 + 1] = (_Float16)v.y;
        Tl[row * 32 + c4 + 2] = (_Float16)v.z;
        Tl[row * 32 + c4 + 3] = (_Float16)v.w;
    }
    __syncthreads();

    _Float16* dst = (which ? Whp : Wxp) + (size_t)f * 16384;
#pragma unroll
    for (int i = 0; i < 8; ++i) {
        int gi  = tid * 8 + i;
        int hn  = gi >> 10;
        int kc  = (gi >> 6) & 15;
        int ln  = gi & 63;
        int l15 = ln & 15, l16 = ln >> 4;
        half8 v;
#pragma unroll
        for (int j = 0; j < 8; ++j)
            v[j] = Tl[(kc * 32 + l16 * 8 + j) * 32 + hn * 16 + l15];
        *reinterpret_cast<half8*>(dst + (size_t)gi * 8) = v;
    }
}

// x f32 -> f16 (one pass)
__global__ __launch_bounds__(256) void xhalf_kernel(const float* __restrict__ xf,
                                                    _Float16* __restrict__ xh) {
    const size_t N = (size_t)512 * Tt * Dd;
    size_t stride = (size_t)gridDim.x * 256 * 8;
    for (size_t base = ((size_t)blockIdx.x * 256 + threadIdx.x) * 8; base < N; base += stride) {
        float4 a = *reinterpret_cast<const float4*>(xf + base);
        float4 b = *reinterpret_cast<const float4*>(xf + base + 4);
        half8 v;
        v[0] = (_Float16)a.x; v[1] = (_Float16)a.y; v[2] = (_Float16)a.z; v[3] = (_Float16)a.w;
        v[4] = (_Float16)b.x; v[5] = (_Float16)b.y; v[6] = (_Float16)b.z; v[7] = (_Float16)b.w;
        *reinterpret_cast<half8*>(xh + base) = v;
    }
}

__global__ __launch_bounds__(512, 2) void lstm_all(
    const float* __restrict__ xf, const _Float16* __restrict__ xh, int usexh,
    const _Float16* __restrict__ Wxp, const _Float16* __restrict__ Whp,
    const float* __restrict__ bias, _Float16* __restrict__ h0,
    _Float16* __restrict__ h1, unsigned int* __restrict__ flags,
    float* __restrict__ out) {

    __shared__ __align__(16) char smem[SMEM_SZ];

    const int tid = threadIdx.x, lane = tid & 63;
    const int wv8 = tid >> 6;            // wave 0..7
    const int g8  = wv8 >> 1;            // gate 0..3
    const int nh  = wv8 & 1;             // 16-col half of the gate's 32
    const int l15 = lane & 15, l16 = lane >> 4;
    const int bid = blockIdx.x;
    const int grp = bid & 15;                         // row group id
    const int rt = (bid & 7) * 2 + ((bid >> 3) & 1);  // row tile 0..15
    const int ct = bid >> 4;                          // col tile 0..15

    // ---------- W fragments -> registers (16+16 half8 = 128 VGPR target) ----------
    half8 wxr[16], whr[16];
    {
        const half8* wxs = reinterpret_cast<const half8*>(Wxp)
                           + (size_t)(ct * 4 + g8) * 2048 + nh * 1024;
        const half8* whs = reinterpret_cast<const half8*>(Whp)
                           + (size_t)(ct * 4 + g8) * 2048 + nh * 1024;
#pragma unroll
        for (int kc = 0; kc < 16; ++kc) {
            wxr[kc] = wxs[kc * 64 + lane];
            whr[kc] = whs[kc * 64 + lane];
        }
    }

    const float biasv = bias[g8 * Hh + ct * 32 + nh * 16 + l15] + (g8 == 2 ? 1.0f : 0.0f);

    const int srow = tid >> 4, sl16 = tid & 15;       // gather / staging: row, chunk
    const int erow = tid >> 4, ecol2 = (tid & 15) * 2; // pointwise: 2 cols/thread
    const int sswz = (srow & 7) << 4;
    float creg[2] = {0.f, 0.f};

    f32x4 accG0, accG1;                  // zx GEMM accumulators (rows 0-15 / 16-31)

    // conflict-free chunk mapping: lane (srow, sl16) handles elements
    // c*128 + sl16*8 .. +7 of its row (16 lanes x 16B contiguous per c)
    auto xload = [&](int g, half8 xl[4]) {
        if (usexh) {
            const _Float16* xr = xh + ((size_t)(rt * 32 + srow) * Tt + g) * Dd + sl16 * 8;
#pragma unroll
            for (int c = 0; c < 4; ++c)
                xl[c] = *reinterpret_cast<const half8*>(xr + c * 128);
        } else {
            const float* xr = xf + ((size_t)(rt * 32 + srow) * Tt + g) * Dd + sl16 * 8;
#pragma unroll
            for (int c = 0; c < 4; ++c) {
                float4 p0 = *reinterpret_cast<const float4*>(xr + c * 128);
                float4 p1 = *reinterpret_cast<const float4*>(xr + c * 128 + 4);
                half8 v;
                v[0] = (_Float16)p0.x; v[1] = (_Float16)p0.y;
                v[2] = (_Float16)p0.z; v[3] = (_Float16)p0.w;
                v[4] = (_Float16)p1.x; v[5] = (_Float16)p1.y;
                v[6] = (_Float16)p1.z; v[7] = (_Float16)p1.w;
                xl[c] = v;
            }
        }
    };
    auto xwrite = [&](int xb, half8 xl[4]) {
        char* xbase = smem + X_OFF + xb * 32768 + srow * 1024;
#pragma unroll
        for (int c = 0; c < 4; ++c)
            *reinterpret_cast<half8*>(xbase + ((c * 256 + sl16 * 16) ^ sswz)) = xl[c];
    };

    auto gemm_range = [&](int xb, int k0, int k1) {
        const char* xbase = smem + X_OFF + xb * 32768;
#pragma unroll
        for (int kc = k0; kc < k1; ++kc) {
            int go = kc * 64 + l16 * 16;
            half8 a0 = *reinterpret_cast<const half8*>(
                xbase + l15 * 1024 + (go ^ ((l15 & 7) << 4)));
            half8 a1 = *reinterpret_cast<const half8*>(
                xbase + (16 + l15) * 1024 + (go ^ ((l15 & 7) << 4)));
            accG0 = MF(a0, wxr[kc], accG0);
            accG1 = MF(a1, wxr[kc], accG1);
        }
    };

    auto ring_write = [&](int slot) {
        half8 z;
#pragma unroll
        for (int r = 0; r < 4; ++r) {
            z[r]     = (_Float16)accG0[r];
            z[4 + r] = (_Float16)accG1[r];
        }
        *reinterpret_cast<half8*>(smem + R_OFF + slot * 8192 + wv8 * 1024 + lane * 16) = z;
    };

    // ---------- prologue: zx(0..3), then x(4) staged into buffer 0 ----------
#pragma unroll 1
    for (int p = 0; p < 4; ++p) {
        { half8 xl[4]; xload(p, xl); xwrite(p & 1, xl); }
        __syncthreads();
        accG0 = f32x4{biasv, biasv, biasv, biasv}; accG1 = accG0;
        gemm_range(p & 1, 0, 16);
        ring_write(p);
        __syncthreads();
    }
    { half8 xl[4]; xload(4, xl); xwrite(0, xl); }
    __syncthreads();

    // ---------- main loop ----------
#pragma unroll 1
    for (int t = 0; t < Tt; ++t) {
        const int xb = t & 1;
        const int slot = t & 3;
        const bool do_g  = (t + 4) < Tt;
        const bool do_g2 = (t + 5) < Tt;
        const _Float16* hin = (t & 1) ? h1 : h0;
        _Float16* hout      = (t & 1) ? h0 : h1;

        half8 xl[4];
        if (do_g2) xload(t + 5, xl);     // issue early; LDS-write late (T14)

        if (do_g) {
            accG0 = f32x4{biasv, biasv, biasv, biasv}; accG1 = accG0;
            gemm_range(xb, 0, 8);        // fills poll slack
        }

        // acc init from zx ring (read slot before rewrite below)
        f32x4 acc0, acc1;
        {
            half8 z = *reinterpret_cast<const half8*>(
                smem + R_OFF + slot * 8192 + wv8 * 1024 + lane * 16);
#pragma unroll
            for (int r = 0; r < 4; ++r) { acc0[r] = (float)z[r]; acc1[r] = (float)z[4 + r]; }
        }

        // poll producers of this row group (64B-spaced flags, sc1 relaxed)
        if (tid < 16) {
            while (__hip_atomic_load(&flags[((unsigned)grp + 16u * (unsigned)tid) * 16u],
                                     __ATOMIC_RELAXED, __HIP_MEMORY_SCOPE_AGENT)
                   < (unsigned)t)
                __builtin_amdgcn_s_sleep(1);
        }
        __syncthreads();

        // cooperative h gather: 8 x 8B sc1 burst (conflict-free chunk mapping)
        const u64* hq = reinterpret_cast<const u64*>(
                            hin + (size_t)(rt * 32 + srow) * Hh) + sl16 * 2;
        u64 hr[8];
#pragma unroll
        for (int c = 0; c < 4; ++c) {
            hr[2 * c]     = __hip_atomic_load(hq + c * 32,     __ATOMIC_RELAXED,
                                              __HIP_MEMORY_SCOPE_AGENT);
            hr[2 * c + 1] = __hip_atomic_load(hq + c * 32 + 1, __ATOMIC_RELAXED,
                                              __HIP_MEMORY_SCOPE_AGENT);
        }

        if (do_g) {                      // fills gather slack
            gemm_range(xb, 8, 16);
            ring_write(slot);
        }

        // stage h tile into LDS (waits the gather; conflict-free writes)
        {
            char* hb = smem + H_OFF + srow * 1024;
#pragma unroll
            for (int c = 0; c < 4; ++c)
                *reinterpret_cast<half8*>(hb + ((c * 256 + sl16 * 16) ^ sswz)) =
                    mk16(hr[2 * c], hr[2 * c + 1]);
        }
        __syncthreads();

        // recurrence: 32 MFMAs/wave
#pragma unroll
        for (int kc = 0; kc < 16; ++kc) {
            int go = kc * 64 + l16 * 16;
            half8 a0 = *reinterpret_cast<const half8*>(
                smem + H_OFF + l15 * 1024 + (go ^ ((l15 & 7) << 4)));
            half8 a1 = *reinterpret_cast<const half8*>(
                smem + H_OFF + (16 + l15) * 1024 + (go ^ ((l15 & 7) << 4)));
            acc0 = MF(a0, whr[kc], acc0);
            acc1 = MF(a1, whr[kc], acc1);
        }

        // Z scatter (swizzled [4][32][32] f32); wave covers 16-col half nh
#pragma unroll
        for (int reg = 0; reg < 4; ++reg) {
            int zr = l16 * 4 + reg;       // C/D: col=lane&15, row=(lane>>4)*4+reg
            int cb = ((nh * 16 + l15) * 4) ^ ((zr & 7) << 4);
            *reinterpret_cast<float*>(smem + Z_OFF + (g8 * 32 + zr) * 128 + cb)      = acc0[reg];
            *reinterpret_cast<float*>(smem + Z_OFF + (g8 * 32 + 16 + zr) * 128 + cb) = acc1[reg];
        }
        __syncthreads();

        // pointwise c/h update: 2 cols per thread
        float hv[2];
        {
            int swz = (ecol2 * 4) ^ ((erow & 7) << 4);
            f32x2 vi = *reinterpret_cast<const f32x2*>(smem + Z_OFF + (0 * 32 + erow) * 128 + swz);
            f32x2 vj = *reinterpret_cast<const f32x2*>(smem + Z_OFF + (1 * 32 + erow) * 128 + swz);
            f32x2 vf = *reinterpret_cast<const f32x2*>(smem + Z_OFF + (2 * 32 + erow) * 128 + swz);
            f32x2 vo = *reinterpret_cast<const f32x2*>(smem + Z_OFF + (3 * 32 + erow) * 128 + swz);
#pragma unroll
            for (int q = 0; q < 2; ++q) {
                float cn = creg[q] * sigm(vf[q]) + sigm(vi[q]) * tanhfast(vj[q]);
                creg[q] = cn;
                hv[q] = tanhfast(cn) * sigm(vo[q]);
            }
        }
        {
            size_t off = (size_t)(rt * 32 + erow) * Hh + ct * 32 + ecol2;
            unsigned hraw = (unsigned)__builtin_bit_cast(unsigned short, (_Float16)hv[0])
                          | ((unsigned)__builtin_bit_cast(unsigned short, (_Float16)hv[1]) << 16);
            __hip_atomic_store(reinterpret_cast<unsigned*>(hout) + (off >> 1), hraw,
                               __ATOMIC_RELAXED, __HIP_MEMORY_SCOPE_AGENT);
            if (t == Tt - 1) {
                f32x2 fo; fo[0] = hv[0]; fo[1] = hv[1];
                *reinterpret_cast<f32x2*>(out + off) = fo;
            }
        }

        // write next x tile into the other buffer (loads issued at head)
        if (do_g2) xwrite((t + 1) & 1, xl);

        // drain h stores + x staging (syncthreads waits vmcnt/lgkm), post flag
        __syncthreads();
        if (t < Tt - 1 && tid == 0)
            __hip_atomic_store(&flags[bid * 16], (unsigned)(t + 1),
                               __ATOMIC_RELAXED, __HIP_MEMORY_SCOPE_AGENT);
    }
}

extern "C" void kernel_launch(void* const* d_in, const int* in_sizes, int n_in,
                              void* d_out, int out_size, void* d_ws, size_t ws_size,
                              hipStream_t stream) {
    const float* x  = (const float*)d_in[0];   // [512,128,512] f32
    const float* W  = (const float*)d_in[1];   // [1024,2048] f32
    const float* bb = (const float*)d_in[2];   // [2048] f32
    float* out = (float*)d_out;                // [512,512] f32

    char* ws = (char*)d_ws;
    _Float16* Wxp = (_Float16*)ws;                                   // 2 MB
    _Float16* Whp = (_Float16*)(ws + (2u << 20));                    // 2 MB
    _Float16* h0  = (_Float16*)(ws + (4u << 20));                    // 512 KB
    _Float16* h1  = (_Float16*)(ws + (4u << 20) + (512u << 10));     // 512 KB
    unsigned int* flags = (unsigned int*)(ws + (5u << 20));          // 256 x 64B
    _Float16* xh = (_Float16*)(ws + (6u << 20));                     // 64 MB (optional)

    const size_t xh_bytes = (size_t)512 * Tt * Dd * sizeof(_Float16);
    int usexh = (ws_size >= (size_t)(6u << 20) + xh_bytes) ? 1 : 0;

    hipMemsetAsync(h0, 0, (size_t)512 * Hh * sizeof(_Float16), stream);
    hipMemsetAsync((void*)flags, 0, 16384, stream);
    pack_kernel<<<128, 256, 0, stream>>>(W, Wxp, Whp);
    if (usexh) xhalf_kernel<<<4096, 256, 0, stream>>>(x, xh);
    lstm_all<<<256, 512, 0, stream>>>(x, xh, usexh, Wxp, Whp, bb, h0, h1, flags, out);
}